// Round 1
// baseline (258.874 us; speedup 1.0000x reference)
//
#include <hip/hip_runtime.h>
#include <hip/hip_bf16.h>
#include <stdint.h>

typedef __attribute__((ext_vector_type(4))) float f32x4;
typedef __attribute__((ext_vector_type(8))) __bf16 bf16x8;
typedef __attribute__((ext_vector_type(4))) __bf16 bf16x4;

#define DEVI __device__ __forceinline__

static constexpr int S_  = 2048;
static constexpr int D_  = 1024;
static constexpr int H_  = 16;
static constexpr int HD_ = 64;
static constexpr int M_  = 2 * S_;   // B*S = 4096 token rows

DEVI void gload_lds16(const void* gsrc, void* ldst) {
  __builtin_amdgcn_global_load_lds(
      (__attribute__((address_space(1))) void*)(void*)gsrc,
      (__attribute__((address_space(3))) void*)ldst, 16, 0, 0);
}

__global__ __launch_bounds__(256) void cvt_bf16_kernel(
    const float* __restrict__ in, __bf16* __restrict__ out, int n4) {
  int i = blockIdx.x * 256 + threadIdx.x;
  if (i >= n4) return;
  float4 v = reinterpret_cast<const float4*>(in)[i];
  bf16x4 o;
  o[0] = (__bf16)v.x; o[1] = (__bf16)v.y; o[2] = (__bf16)v.z; o[3] = (__bf16)v.w;
  reinterpret_cast<bf16x4*>(out)[i] = o;
}

// tab[s*32+f] = {cos, sin}(s * 10000^(-2f/64))
__global__ __launch_bounds__(256) void rope_table_kernel(float* __restrict__ tab) {
  int i = blockIdx.x * 256 + threadIdx.x;   // S*32 threads
  int s = i >> 5, f = i & 31;
  float freq = powf(10000.0f, -(float)(2 * f) / (float)HD_);
  float ang = (float)s * freq;
  tab[2 * i]     = cosf(ang);
  tab[2 * i + 1] = sinf(ang);
}

// C[m][n] = sum_k A[m][k] * W[n][k]   (both K-major, bf16, fp32 acc)
// MODE 0: Cf[m*N+n] = fp32 result (O projection -> d_out)
// MODE 1: bf16 out, head-split layout [B][H][S][hd]; blockIdx.z: 0=Q(+RoPE),
//         1=K(+RoPE), 2=V (no RoPE)
template <int MODE>
__global__ __launch_bounds__(256) void gemm_bt(
    const __bf16* __restrict__ A, const __bf16* __restrict__ W0,
    const __bf16* __restrict__ W1, const __bf16* __restrict__ W2,
    float* __restrict__ Cf, __bf16* __restrict__ Cq, __bf16* __restrict__ Ck,
    __bf16* __restrict__ Cv, const float* __restrict__ tab,
    int M, int N, int K) {
  constexpr int BM = 128, BN = 128, BK = 32;
  __shared__ __attribute__((aligned(16))) __bf16 As[BM * BK];
  __shared__ __attribute__((aligned(16))) __bf16 Bs[BN * BK];
  const int tid  = threadIdx.x;
  const int lane = tid & 63;
  const int wv   = tid >> 6;
  const int m0 = blockIdx.x * BM;
  const int n0 = blockIdx.y * BN;
  const __bf16* W = (MODE == 0) ? W0
                    : (blockIdx.z == 0 ? W0 : (blockIdx.z == 1 ? W1 : W2));
  const int wm = (wv >> 1) * 64, wn = (wv & 1) * 64;
  const int arow = lane & 15;
  const int kgrp = (lane >> 4) * 8;

  f32x4 acc[4][4];
#pragma unroll
  for (int i = 0; i < 4; i++)
#pragma unroll
    for (int j = 0; j < 4; j++) acc[i][j] = f32x4{0.f, 0.f, 0.f, 0.f};

  for (int k0 = 0; k0 < K; k0 += BK) {
    __syncthreads();   // previous iteration's LDS reads done
#pragma unroll
    for (int j = 0; j < 2; ++j) {
      int c   = (wv * 2 + j) * 64 + lane;  // 16B chunk id, 0..511
      int row = c >> 2;
      int kc  = (c & 3) * 8;
      // LDS dest is wave-uniform base + lane*16 (hardware rule)
      gload_lds16(A + (size_t)(m0 + row) * K + k0 + kc,
                  As + (size_t)(wv * 2 + j) * 512);
      gload_lds16(W + (size_t)(n0 + row) * K + k0 + kc,
                  Bs + (size_t)(wv * 2 + j) * 512);
    }
    asm volatile("s_waitcnt vmcnt(0)" ::: "memory");
    __syncthreads();
    bf16x8 af[4], bw[4];
#pragma unroll
    for (int i = 0; i < 4; i++)
      af[i] = *reinterpret_cast<const bf16x8*>(As + (wm + i * 16 + arow) * BK + kgrp);
#pragma unroll
    for (int i = 0; i < 4; i++)
      bw[i] = *reinterpret_cast<const bf16x8*>(Bs + (wn + i * 16 + arow) * BK + kgrp);
#pragma unroll
    for (int i = 0; i < 4; i++)
#pragma unroll
      for (int j = 0; j < 4; j++)
        acc[i][j] = __builtin_amdgcn_mfma_f32_16x16x32_bf16(af[i], bw[j], acc[i][j], 0, 0, 0);
  }

  // epilogue. C/D layout: col = lane&15, row = (lane>>4)*4 + reg  [m89/m91]
#pragma unroll
  for (int i = 0; i < 4; i++) {
#pragma unroll
    for (int j = 0; j < 4; j++) {
#pragma unroll
      for (int r = 0; r < 4; r++) {
        int m = m0 + wm + i * 16 + (lane >> 4) * 4 + r;
        int n = n0 + wn + j * 16 + arow;
        float v = acc[i][j][r];
        if (MODE == 0) {
          Cf[(size_t)m * N + n] = v;
        } else {
          int bb = m >> 11, s = m & (S_ - 1);
          int h = n >> 6, d = n & 63;
          size_t oidx = ((size_t)(bb * H_ + h) * S_ + s) * HD_ + d;
          // adjacent feature columns live in adjacent lanes (n bit0 = lane bit0)
          float other = __shfl_xor(v, 1, 64);
          if (blockIdx.z == 2) {
            Cv[oidx] = (__bf16)v;
          } else {
            int fi = d >> 1;
            float cs = tab[(s * 32 + fi) * 2];
            float sn = tab[(s * 32 + fi) * 2 + 1];
            float rv = (d & 1) ? (other * sn + v * cs) : (v * cs - other * sn);
            __bf16* Co = (blockIdx.z == 0) ? Cq : Ck;
            Co[oidx] = (__bf16)rv;
          }
        }
      }
    }
  }
}

// Flash attention, causal. Grid: (S/64 q-tiles, B*H). 4 waves x 16 q-rows.
// K staged [key][d] XOR-swizzled; V staged transposed [d][key] XOR-swizzled.
__global__ __launch_bounds__(256) void attn_kernel(
    const __bf16* __restrict__ Q, const __bf16* __restrict__ K,
    const __bf16* __restrict__ V, __bf16* __restrict__ O) {
  __shared__ __attribute__((aligned(16))) __bf16 Ks[64 * 64];
  __shared__ __attribute__((aligned(16))) __bf16 Vs[64 * 64];
  __shared__ __attribute__((aligned(16))) __bf16 Ps[4 * 16 * 64];
  const int tid = threadIdx.x, lane = tid & 63, wv = tid >> 6;
  const int q0 = blockIdx.x * 64;
  const int bh = blockIdx.y;
  const int b = bh >> 4, h = bh & 15;
  const __bf16* Qb = Q + (size_t)bh * S_ * HD_;
  const __bf16* Kb = K + (size_t)bh * S_ * HD_;
  const __bf16* Vb = V + (size_t)bh * S_ * HD_;
  const int arow = lane & 15, g = lane >> 4;
  const int qw = q0 + wv * 16;

  bf16x8 aq[2];
#pragma unroll
  for (int j = 0; j < 2; j++)
    aq[j] = *reinterpret_cast<const bf16x8*>(Qb + (size_t)(qw + arow) * HD_ + j * 32 + g * 8);

  f32x4 po[4];
#pragma unroll
  for (int dt = 0; dt < 4; dt++) po[dt] = f32x4{0.f, 0.f, 0.f, 0.f};
  float mrow[4], lrow[4];
#pragma unroll
  for (int r = 0; r < 4; r++) { mrow[r] = -1e30f; lrow[r] = 0.f; }

  const int nkv = blockIdx.x + 1;   // causal: tiles 0..q0/64
  for (int kt = 0; kt < nkv; ++kt) {
    const int k0 = kt * 64;
    __syncthreads();   // previous tile fully consumed
#pragma unroll
    for (int j = 0; j < 2; ++j) {
      int c = tid + j * 256;               // 512 chunks of 8 elems
      int key = c >> 3, dc = c & 7;
      bf16x8 kv8 = *reinterpret_cast<const bf16x8*>(Kb + (size_t)(k0 + key) * HD_ + dc * 8);
      int byt = (key * 128 + dc * 16) ^ ((key & 7) << 4);
      *reinterpret_cast<bf16x8*>((char*)Ks + byt) = kv8;
      bf16x8 vv8 = *reinterpret_cast<const bf16x8*>(Vb + (size_t)(k0 + key) * HD_ + dc * 8);
#pragma unroll
      for (int e = 0; e < 8; ++e) {
        int d = dc * 8 + e;
        int byv = (d * 128 + key * 2) ^ ((d & 7) << 4);
        *reinterpret_cast<__bf16*>((char*)Vs + byv) = vv8[e];
      }
    }
    __syncthreads();

    // S = Q K^T : 16 q-rows x 64 keys
    f32x4 sc[4];
#pragma unroll
    for (int ct = 0; ct < 4; ct++) {
      sc[ct] = f32x4{0.f, 0.f, 0.f, 0.f};
#pragma unroll
      for (int j = 0; j < 2; j++) {
        int key = ct * 16 + arow;
        int byt = (key * 128 + j * 64 + g * 16) ^ ((key & 7) << 4);
        bf16x8 kb = *reinterpret_cast<const bf16x8*>((const char*)Ks + byt);
        sc[ct] = __builtin_amdgcn_mfma_f32_16x16x32_bf16(aq[j], kb, sc[ct], 0, 0, 0);
      }
    }

    // mask + scale + online softmax (16-lane row reduce, all lanes busy)
    float p[4][4];
#pragma unroll
    for (int r = 0; r < 4; r++) {
      int qg = qw + g * 4 + r;
      float mx = -1e30f;
#pragma unroll
      for (int ct = 0; ct < 4; ct++) {
        int kg = k0 + ct * 16 + arow;
        float sv = (kg <= qg) ? sc[ct][r] * 0.125f : -1e30f;
        p[ct][r] = sv;
        mx = fmaxf(mx, sv);
      }
#pragma unroll
      for (int off = 1; off < 16; off <<= 1) mx = fmaxf(mx, __shfl_xor(mx, off, 64));
      float mnew = fmaxf(mrow[r], mx);
      float corr = __expf(mrow[r] - mnew);
      mrow[r] = mnew;
      float rs = 0.f;
#pragma unroll
      for (int ct = 0; ct < 4; ct++) {
        float pv = __expf(p[ct][r] - mnew);
        p[ct][r] = pv;
        rs += pv;
      }
#pragma unroll
      for (int off = 1; off < 16; off <<= 1) rs += __shfl_xor(rs, off, 64);
      lrow[r] = lrow[r] * corr + rs;
#pragma unroll
      for (int dt = 0; dt < 4; dt++) po[dt][r] *= corr;
    }

    // P -> per-wave LDS (bf16, swizzled) to re-shape into MFMA A-operand
    __bf16* Pw = Ps + wv * 16 * 64;
#pragma unroll
    for (int r = 0; r < 4; r++) {
      int qr = g * 4 + r;
#pragma unroll
      for (int ct = 0; ct < 4; ct++) {
        int kk = ct * 16 + arow;
        int byp = (qr * 128 + kk * 2) ^ ((qr & 7) << 4);
        *reinterpret_cast<__bf16*>((char*)Pw + byp) = (__bf16)p[ct][r];
      }
    }

    // O += P V
#pragma unroll
    for (int dt = 0; dt < 4; dt++) {
#pragma unroll
      for (int j2 = 0; j2 < 2; j2++) {
        int byp = (arow * 128 + j2 * 64 + g * 16) ^ ((arow & 7) << 4);
        bf16x8 pa = *reinterpret_cast<const bf16x8*>((const char*)Pw + byp);
        int d = dt * 16 + arow;
        int byv = (d * 128 + j2 * 64 + g * 16) ^ ((d & 7) << 4);
        bf16x8 vb = *reinterpret_cast<const bf16x8*>((const char*)Vs + byv);
        po[dt] = __builtin_amdgcn_mfma_f32_16x16x32_bf16(pa, vb, po[dt], 0, 0, 0);
      }
    }
  }

  // write attn output as [token][feature] rows for the O-projection GEMM
#pragma unroll
  for (int dt = 0; dt < 4; dt++) {
#pragma unroll
    for (int r = 0; r < 4; r++) {
      int qg = qw + g * 4 + r;
      int d = dt * 16 + arow;
      float ov = po[dt][r] / lrow[r];
      O[(size_t)(b * S_ + qg) * D_ + h * HD_ + d] = (__bf16)ov;
    }
  }
}

extern "C" void kernel_launch(void* const* d_in, const int* in_sizes, int n_in,
                              void* d_out, int out_size, void* d_ws, size_t ws_size,
                              hipStream_t stream) {
  const float* x  = (const float*)d_in[0];
  const float* wq = (const float*)d_in[1];
  const float* wk = (const float*)d_in[2];
  const float* wv = (const float*)d_in[3];
  const float* wo = (const float*)d_in[4];
  float* out = (float*)d_out;

  char* w = (char*)d_ws;
  __bf16* xb  = (__bf16*)(w);                    // 8 MB
  __bf16* wqb = (__bf16*)(w + (8u  << 20));      // 2 MB each
  __bf16* wkb = (__bf16*)(w + (10u << 20));
  __bf16* wvb = (__bf16*)(w + (12u << 20));
  __bf16* wob = (__bf16*)(w + (14u << 20));
  __bf16* qws = (__bf16*)(w + (16u << 20));      // 8 MB each, [B][H][S][hd]
  __bf16* kws = (__bf16*)(w + (24u << 20));
  __bf16* vws = (__bf16*)(w + (32u << 20));
  __bf16* aws = (__bf16*)(w + (40u << 20));      // attn out, [token][feature]
  float*  tab = (float*)(w + (48u << 20));       // 512 KB rope table

  cvt_bf16_kernel<<<M_ * D_ / 4 / 256, 256, 0, stream>>>(x,  xb,  M_ * D_ / 4);
  cvt_bf16_kernel<<<D_ * D_ / 4 / 256, 256, 0, stream>>>(wq, wqb, D_ * D_ / 4);
  cvt_bf16_kernel<<<D_ * D_ / 4 / 256, 256, 0, stream>>>(wk, wkb, D_ * D_ / 4);
  cvt_bf16_kernel<<<D_ * D_ / 4 / 256, 256, 0, stream>>>(wv, wvb, D_ * D_ / 4);
  cvt_bf16_kernel<<<D_ * D_ / 4 / 256, 256, 0, stream>>>(wo, wob, D_ * D_ / 4);
  rope_table_kernel<<<(S_ * 32) / 256, 256, 0, stream>>>(tab);

  dim3 g1(M_ / 128, D_ / 128, 3);
  gemm_bt<1><<<g1, 256, 0, stream>>>(xb, wqb, wkb, wvb,
                                     nullptr, qws, kws, vws, tab, M_, D_, D_);
  attn_kernel<<<dim3(S_ / 64, 2 * H_), 256, 0, stream>>>(qws, kws, vws, aws);
  dim3 g0(M_ / 128, D_ / 128, 1);
  gemm_bt<0><<<g0, 256, 0, stream>>>(aws, wob, wob, wob,
                                     out, nullptr, nullptr, nullptr, nullptr,
                                     M_, D_, D_);
}

// Round 2
// 166.459 us; speedup vs baseline: 1.5552x; 1.5552x over previous
//
#include <hip/hip_runtime.h>
#include <hip/hip_bf16.h>
#include <stdint.h>

typedef __attribute__((ext_vector_type(4))) float f32x4;
typedef __attribute__((ext_vector_type(8))) __bf16 bf16x8;
typedef __attribute__((ext_vector_type(4))) __bf16 bf16x4;

#define DEVI __device__ __forceinline__

static constexpr int S_  = 2048;
static constexpr int D_  = 1024;
static constexpr int H_  = 16;
static constexpr int HD_ = 64;
static constexpr int M_  = 2 * S_;   // B*S = 4096 token rows

DEVI void gload_lds16(const void* gsrc, void* ldst) {
  __builtin_amdgcn_global_load_lds(
      (__attribute__((address_space(1))) void*)(void*)gsrc,
      (__attribute__((address_space(3))) void*)ldst, 16, 0, 0);
}

DEVI float fexp2(float x) {
  float r;
  asm("v_exp_f32 %0, %1" : "=v"(r) : "v"(x));
  return r;
}

__global__ __launch_bounds__(256) void cvt_bf16_kernel(
    const float* __restrict__ in, __bf16* __restrict__ out, int n4) {
  int i = blockIdx.x * 256 + threadIdx.x;
  if (i >= n4) return;
  float4 v = reinterpret_cast<const float4*>(in)[i];
  bf16x4 o;
  o[0] = (__bf16)v.x; o[1] = (__bf16)v.y; o[2] = (__bf16)v.z; o[3] = (__bf16)v.w;
  reinterpret_cast<bf16x4*>(out)[i] = o;
}

// tab[s*32+f] = {cos, sin}(s * 10000^(-2f/64))
__global__ __launch_bounds__(256) void rope_table_kernel(float* __restrict__ tab) {
  int i = blockIdx.x * 256 + threadIdx.x;   // S*32 threads
  int s = i >> 5, f = i & 31;
  float freq = powf(10000.0f, -(float)(2 * f) / (float)HD_);
  float ang = (float)s * freq;
  tab[2 * i]     = cosf(ang);
  tab[2 * i + 1] = sinf(ang);
}

// C[m][n] = sum_k A[m][k] * W[n][k]   (both K-major, bf16, fp32 acc)
template <int MODE>
__global__ __launch_bounds__(256) void gemm_bt(
    const __bf16* __restrict__ A, const __bf16* __restrict__ W0,
    const __bf16* __restrict__ W1, const __bf16* __restrict__ W2,
    float* __restrict__ Cf, __bf16* __restrict__ Cq, __bf16* __restrict__ Ck,
    __bf16* __restrict__ Cv, const float* __restrict__ tab,
    int M, int N, int K) {
  constexpr int BM = 128, BN = 128, BK = 32;
  __shared__ __attribute__((aligned(16))) __bf16 As[BM * BK];
  __shared__ __attribute__((aligned(16))) __bf16 Bs[BN * BK];
  const int tid  = threadIdx.x;
  const int lane = tid & 63;
  const int wv   = tid >> 6;
  const int m0 = blockIdx.x * BM;
  const int n0 = blockIdx.y * BN;
  const __bf16* W = (MODE == 0) ? W0
                    : (blockIdx.z == 0 ? W0 : (blockIdx.z == 1 ? W1 : W2));
  const int wm = (wv >> 1) * 64, wn = (wv & 1) * 64;
  const int arow = lane & 15;
  const int kgrp = (lane >> 4) * 8;

  f32x4 acc[4][4];
#pragma unroll
  for (int i = 0; i < 4; i++)
#pragma unroll
    for (int j = 0; j < 4; j++) acc[i][j] = f32x4{0.f, 0.f, 0.f, 0.f};

  for (int k0 = 0; k0 < K; k0 += BK) {
    __syncthreads();
#pragma unroll
    for (int j = 0; j < 2; ++j) {
      int c   = (wv * 2 + j) * 64 + lane;
      int row = c >> 2;
      int kc  = (c & 3) * 8;
      gload_lds16(A + (size_t)(m0 + row) * K + k0 + kc,
                  As + (size_t)(wv * 2 + j) * 512);
      gload_lds16(W + (size_t)(n0 + row) * K + k0 + kc,
                  Bs + (size_t)(wv * 2 + j) * 512);
    }
    asm volatile("s_waitcnt vmcnt(0)" ::: "memory");
    __syncthreads();
    bf16x8 af[4], bw[4];
#pragma unroll
    for (int i = 0; i < 4; i++)
      af[i] = *reinterpret_cast<const bf16x8*>(As + (wm + i * 16 + arow) * BK + kgrp);
#pragma unroll
    for (int i = 0; i < 4; i++)
      bw[i] = *reinterpret_cast<const bf16x8*>(Bs + (wn + i * 16 + arow) * BK + kgrp);
#pragma unroll
    for (int i = 0; i < 4; i++)
#pragma unroll
      for (int j = 0; j < 4; j++)
        acc[i][j] = __builtin_amdgcn_mfma_f32_16x16x32_bf16(af[i], bw[j], acc[i][j], 0, 0, 0);
  }

  // epilogue. C/D layout: col = lane&15, row = (lane>>4)*4 + reg  [m89/m91]
#pragma unroll
  for (int i = 0; i < 4; i++) {
#pragma unroll
    for (int j = 0; j < 4; j++) {
#pragma unroll
      for (int r = 0; r < 4; r++) {
        int m = m0 + wm + i * 16 + (lane >> 4) * 4 + r;
        int n = n0 + wn + j * 16 + arow;
        float v = acc[i][j][r];
        if (MODE == 0) {
          Cf[(size_t)m * N + n] = v;
        } else {
          int bb = m >> 11, s = m & (S_ - 1);
          int h = n >> 6, d = n & 63;
          size_t oidx = ((size_t)(bb * H_ + h) * S_ + s) * HD_ + d;
          float other = __shfl_xor(v, 1, 64);
          if (blockIdx.z == 2) {
            Cv[oidx] = (__bf16)v;
          } else {
            int fi = d >> 1;
            float cs = tab[(s * 32 + fi) * 2];
            float sn = tab[(s * 32 + fi) * 2 + 1];
            float rv = (d & 1) ? (other * sn + v * cs) : (v * cs - other * sn);
            __bf16* Co = (blockIdx.z == 0) ? Cq : Ck;
            Co[oidx] = (__bf16)rv;
          }
        }
      }
    }
  }
}

// V [bh][s][d=64] -> Vt [bh][d][s].  Tile 64s x 64d per block.
__global__ __launch_bounds__(256) void vtrans_kernel(
    const __bf16* __restrict__ V, __bf16* __restrict__ Vt) {
  __shared__ __attribute__((aligned(16))) char T[64 * 144]; // row d, 144B stride
  const int bh = blockIdx.y, s0 = blockIdx.x * 64;
  const __bf16* Vb = V + (size_t)bh * S_ * HD_;
  __bf16* Vtb = Vt + (size_t)bh * HD_ * S_;
  const int tid = threadIdx.x;
#pragma unroll
  for (int j = 0; j < 2; ++j) {
    int c = tid + j * 256;            // s = c>>3, dc = c&7
    int s = c >> 3, dc = c & 7;
    bf16x8 v = *reinterpret_cast<const bf16x8*>(Vb + (size_t)(s0 + s) * HD_ + dc * 8);
#pragma unroll
    for (int e = 0; e < 8; ++e) {
      int d = dc * 8 + e;
      int byt = (d * 144 + s * 2) ^ ((dc & 7) << 4);   // spread banks by dc
      *reinterpret_cast<__bf16*>(T + byt) = v[e];
    }
  }
  __syncthreads();
#pragma unroll
  for (int j = 0; j < 2; ++j) {
    int c = tid + j * 256;            // d = c>>3, sc = c&7
    int d = c >> 3, sc = c & 7;
    int byt = (d * 144 + sc * 16) ^ (((d >> 3) & 7) << 4);
    bf16x8 o = *reinterpret_cast<const bf16x8*>(T + byt);
    *reinterpret_cast<bf16x8*>(Vtb + (size_t)d * S_ + s0 + sc * 8) = o;
  }
}

// Flash attention, causal. Grid: (bh=32, pr=16). Block: 4 waves x 16 q-rows,
// two paired q-tiles (pr, 31-pr) => uniform 33 kv-iters per block.
// K staged [key][64d], Vt staged [d][64key]; both XOR-swizzled via
// pre-swizzled global source + linear global_load_lds dest (m173).
__global__ __launch_bounds__(256) void attn_kernel(
    const __bf16* __restrict__ Q, const __bf16* __restrict__ K,
    const __bf16* __restrict__ Vt, __bf16* __restrict__ O) {
  __shared__ __attribute__((aligned(16))) __bf16 Ks[2][64 * 64];
  __shared__ __attribute__((aligned(16))) __bf16 Vs[2][64 * 64];
  __shared__ __attribute__((aligned(16))) __bf16 Ps[4 * 16 * 64];
  const int tid = threadIdx.x, lane = tid & 63, wv = tid >> 6;
  const int bh = blockIdx.x;           // same-head blocks share an XCD's L2
  const int pr = blockIdx.y;
  const int b = bh >> 4, h = bh & 15;
  const __bf16* Qb  = Q  + (size_t)bh * S_ * HD_;
  const __bf16* Kb  = K  + (size_t)bh * S_ * HD_;
  const __bf16* Vtb = Vt + (size_t)bh * HD_ * S_;
  const int arow = lane & 15, g = lane >> 4;
  constexpr float SCL2 = 0.125f * 1.44269504f;   // scale * log2(e)

#define STAGE(K0, BK_, BV_)                                                   \
  do {                                                                        \
    _Pragma("unroll") for (int j = 0; j < 2; ++j) {                           \
      int G = (wv * 2 + j) * 64 + lane;                                       \
      int row = G >> 3, qq = G & 7;                                           \
      int qs = qq ^ (row & 7);                                                \
      gload_lds16(Kb + (size_t)((K0) + row) * HD_ + qs * 8,                   \
                  (BK_) + (wv * 2 + j) * 512);                                \
      gload_lds16(Vtb + (size_t)row * S_ + (K0) + qs * 8,                     \
                  (BV_) + (wv * 2 + j) * 512);                                \
    }                                                                         \
  } while (0)

  for (int seg = 0; seg < 2; ++seg) {
    const int qt = (seg == 0) ? pr : 31 - pr;
    const int q0 = qt * 64;
    const int nkv = qt + 1;
    const int qw = q0 + wv * 16;

    bf16x8 aq[2];
#pragma unroll
    for (int j = 0; j < 2; j++)
      aq[j] = *reinterpret_cast<const bf16x8*>(
          Qb + (size_t)(qw + arow) * HD_ + j * 32 + g * 8);

    f32x4 po[4];
#pragma unroll
    for (int dt = 0; dt < 4; dt++) po[dt] = f32x4{0.f, 0.f, 0.f, 0.f};
    float mrow[4], lrow[4];
#pragma unroll
    for (int r = 0; r < 4; r++) { mrow[r] = -1e30f; lrow[r] = 0.f; }

    STAGE(0, Ks[0], Vs[0]);
    asm volatile("s_waitcnt vmcnt(0)" ::: "memory");
    __syncthreads();

    for (int kt = 0; kt < nkv; ++kt) {
      const int k0 = kt * 64;
      const int cur = kt & 1;
      if (kt + 1 < nkv) STAGE(k0 + 64, Ks[cur ^ 1], Vs[cur ^ 1]);
      const __bf16* Kc = Ks[cur];
      const __bf16* Vc = Vs[cur];

      // S = Q K^T : 16 q-rows x 64 keys
      f32x4 sc4[4];
#pragma unroll
      for (int ct = 0; ct < 4; ct++) {
        sc4[ct] = f32x4{0.f, 0.f, 0.f, 0.f};
        int key = ct * 16 + arow;
#pragma unroll
        for (int j2 = 0; j2 < 2; j2++) {
          int byt = (key * 128 + j2 * 64 + g * 16) ^ ((key & 7) << 4);
          bf16x8 kb = *reinterpret_cast<const bf16x8*>((const char*)Kc + byt);
          sc4[ct] = __builtin_amdgcn_mfma_f32_16x16x32_bf16(aq[j2], kb, sc4[ct], 0, 0, 0);
        }
      }

      // online softmax in exp2 domain; mask only on the diagonal tile
      const bool full = (kt < nkv - 1);
      float p[4][4];
#pragma unroll
      for (int r = 0; r < 4; r++) {
        const int qg = qw + g * 4 + r;
        float mx = -1e30f;
#pragma unroll
        for (int ct = 0; ct < 4; ct++) {
          float sv = sc4[ct][r] * SCL2;
          if (!full) {
            int kg = k0 + ct * 16 + arow;
            sv = (kg <= qg) ? sv : -1e30f;
          }
          p[ct][r] = sv;
          mx = fmaxf(mx, sv);
        }
#pragma unroll
        for (int off = 1; off < 16; off <<= 1) mx = fmaxf(mx, __shfl_xor(mx, off, 64));
        float mnew = fmaxf(mrow[r], mx);
        float corr = fexp2(mrow[r] - mnew);
        mrow[r] = mnew;
        float rs = 0.f;
#pragma unroll
        for (int ct = 0; ct < 4; ct++) {
          float pv = fexp2(p[ct][r] - mnew);
          p[ct][r] = pv;
          rs += pv;
        }
#pragma unroll
        for (int off = 1; off < 16; off <<= 1) rs += __shfl_xor(rs, off, 64);
        lrow[r] = lrow[r] * corr + rs;
#pragma unroll
        for (int dt = 0; dt < 4; dt++) po[dt][r] *= corr;
      }

      // P -> per-wave LDS (bf16, swizzled)
      __bf16* Pw = Ps + wv * 16 * 64;
#pragma unroll
      for (int r = 0; r < 4; r++) {
        int qr = g * 4 + r;
#pragma unroll
        for (int ct = 0; ct < 4; ct++) {
          int kk = ct * 16 + arow;
          int byp = (qr * 128 + kk * 2) ^ ((qr & 7) << 4);
          *reinterpret_cast<__bf16*>((char*)Pw + byp) = (__bf16)p[ct][r];
        }
      }

      // O += P V
#pragma unroll
      for (int dt = 0; dt < 4; dt++) {
        int d = dt * 16 + arow;
#pragma unroll
        for (int j2 = 0; j2 < 2; j2++) {
          int byp = (arow * 128 + j2 * 64 + g * 16) ^ ((arow & 7) << 4);
          bf16x8 pa = *reinterpret_cast<const bf16x8*>((const char*)Pw + byp);
          int byv = (d * 128 + j2 * 64 + g * 16) ^ ((d & 7) << 4);
          bf16x8 vb = *reinterpret_cast<const bf16x8*>((const char*)Vc + byv);
          po[dt] = __builtin_amdgcn_mfma_f32_16x16x32_bf16(pa, vb, po[dt], 0, 0, 0);
        }
      }

      asm volatile("s_waitcnt vmcnt(0)" ::: "memory");
      __syncthreads();
    }

    // write attn output as [token][feature]
#pragma unroll
    for (int r = 0; r < 4; r++) {
      float inv = __builtin_amdgcn_rcpf(lrow[r]);
      int qg = qw + g * 4 + r;
#pragma unroll
      for (int dt = 0; dt < 4; dt++) {
        int d = dt * 16 + arow;
        O[(size_t)(b * S_ + qg) * D_ + h * HD_ + d] = (__bf16)(po[dt][r] * inv);
      }
    }
  }
#undef STAGE
}

extern "C" void kernel_launch(void* const* d_in, const int* in_sizes, int n_in,
                              void* d_out, int out_size, void* d_ws, size_t ws_size,
                              hipStream_t stream) {
  const float* x  = (const float*)d_in[0];
  const float* wq = (const float*)d_in[1];
  const float* wk = (const float*)d_in[2];
  const float* wv = (const float*)d_in[3];
  const float* wo = (const float*)d_in[4];
  float* out = (float*)d_out;

  char* w = (char*)d_ws;
  __bf16* xb  = (__bf16*)(w);                    // 8 MB (reused as Vt later)
  __bf16* wqb = (__bf16*)(w + (8u  << 20));      // 2 MB each
  __bf16* wkb = (__bf16*)(w + (10u << 20));
  __bf16* wvb = (__bf16*)(w + (12u << 20));
  __bf16* wob = (__bf16*)(w + (14u << 20));
  __bf16* qws = (__bf16*)(w + (16u << 20));      // 8 MB each, [B][H][S][hd]
  __bf16* kws = (__bf16*)(w + (24u << 20));
  __bf16* vws = (__bf16*)(w + (32u << 20));
  __bf16* aws = (__bf16*)(w + (40u << 20));      // attn out, [token][feature]
  float*  tab = (float*)(w + (48u << 20));       // 512 KB rope table
  __bf16* vtw = xb;                              // Vt overlays xb (dead after QKV)

  cvt_bf16_kernel<<<M_ * D_ / 4 / 256, 256, 0, stream>>>(x,  xb,  M_ * D_ / 4);
  cvt_bf16_kernel<<<D_ * D_ / 4 / 256, 256, 0, stream>>>(wq, wqb, D_ * D_ / 4);
  cvt_bf16_kernel<<<D_ * D_ / 4 / 256, 256, 0, stream>>>(wk, wkb, D_ * D_ / 4);
  cvt_bf16_kernel<<<D_ * D_ / 4 / 256, 256, 0, stream>>>(wv, wvb, D_ * D_ / 4);
  cvt_bf16_kernel<<<D_ * D_ / 4 / 256, 256, 0, stream>>>(wo, wob, D_ * D_ / 4);
  rope_table_kernel<<<(S_ * 32) / 256, 256, 0, stream>>>(tab);

  dim3 g1(M_ / 128, D_ / 128, 3);
  gemm_bt<1><<<g1, 256, 0, stream>>>(xb, wqb, wkb, wvb,
                                     nullptr, qws, kws, vws, tab, M_, D_, D_);
  vtrans_kernel<<<dim3(S_ / 64, 2 * H_), 256, 0, stream>>>(vws, vtw);
  attn_kernel<<<dim3(2 * H_, S_ / 128), 256, 0, stream>>>(qws, kws, vtw, aws);
  dim3 g0(M_ / 128, D_ / 128, 1);
  gemm_bt<0><<<g0, 256, 0, stream>>>(aws, wob, wob, wob,
                                     out, nullptr, nullptr, nullptr, nullptr,
                                     M_, D_, D_);
}

// Round 3
// 145.408 us; speedup vs baseline: 1.7803x; 1.1448x over previous
//
#include <hip/hip_runtime.h>
#include <hip/hip_bf16.h>
#include <stdint.h>

typedef __attribute__((ext_vector_type(4))) float f32x4;
typedef __attribute__((ext_vector_type(8))) __bf16 bf16x8;
typedef __attribute__((ext_vector_type(4))) __bf16 bf16x4;

#define DEVI __device__ __forceinline__

static constexpr int S_  = 2048;
static constexpr int D_  = 1024;
static constexpr int H_  = 16;
static constexpr int HD_ = 64;
static constexpr int M_  = 2 * S_;   // B*S = 4096 token rows
static constexpr float SCL2 = 0.18033688f;  // 0.125 * log2(e)

DEVI void gload_lds16(const void* gsrc, void* ldst) {
  __builtin_amdgcn_global_load_lds(
      (__attribute__((address_space(1))) void*)(void*)gsrc,
      (__attribute__((address_space(3))) void*)ldst, 16, 0, 0);
}

DEVI float fexp2(float x) {
  float r;
  asm("v_exp_f32 %0, %1" : "=v"(r) : "v"(x));
  return r;
}

__global__ __launch_bounds__(256) void cvt_bf16_kernel(
    const float* __restrict__ in, __bf16* __restrict__ out, int n4) {
  int i = blockIdx.x * 256 + threadIdx.x;
  if (i >= n4) return;
  float4 v = reinterpret_cast<const float4*>(in)[i];
  bf16x4 o;
  o[0] = (__bf16)v.x; o[1] = (__bf16)v.y; o[2] = (__bf16)v.z; o[3] = (__bf16)v.w;
  reinterpret_cast<bf16x4*>(out)[i] = o;
}

// tab[s*32+f] = {cos, sin}(s * 10000^(-2f/64))
__global__ __launch_bounds__(256) void rope_table_kernel(float* __restrict__ tab) {
  int i = blockIdx.x * 256 + threadIdx.x;   // S*32 threads
  int s = i >> 5, f = i & 31;
  float freq = powf(10000.0f, -(float)(2 * f) / (float)HD_);
  float ang = (float)s * freq;
  tab[2 * i]     = cosf(ang);
  tab[2 * i + 1] = sinf(ang);
}

// C[m][n] = sum_k A[m][k] * W[n][k]   (both K-major, bf16, fp32 acc)
template <int MODE>
__global__ __launch_bounds__(256) void gemm_bt(
    const __bf16* __restrict__ A, const __bf16* __restrict__ W0,
    const __bf16* __restrict__ W1, const __bf16* __restrict__ W2,
    float* __restrict__ Cf, __bf16* __restrict__ Cq, __bf16* __restrict__ Ck,
    __bf16* __restrict__ Cv, const float* __restrict__ tab,
    int M, int N, int K) {
  constexpr int BM = 128, BN = 128, BK = 32;
  __shared__ __attribute__((aligned(16))) __bf16 As[BM * BK];
  __shared__ __attribute__((aligned(16))) __bf16 Bs[BN * BK];
  const int tid  = threadIdx.x;
  const int lane = tid & 63;
  const int wv   = tid >> 6;
  const int m0 = blockIdx.x * BM;
  const int n0 = blockIdx.y * BN;
  const __bf16* W = (MODE == 0) ? W0
                    : (blockIdx.z == 0 ? W0 : (blockIdx.z == 1 ? W1 : W2));
  const int wm = (wv >> 1) * 64, wn = (wv & 1) * 64;
  const int arow = lane & 15;
  const int kgrp = (lane >> 4) * 8;

  f32x4 acc[4][4];
#pragma unroll
  for (int i = 0; i < 4; i++)
#pragma unroll
    for (int j = 0; j < 4; j++) acc[i][j] = f32x4{0.f, 0.f, 0.f, 0.f};

  for (int k0 = 0; k0 < K; k0 += BK) {
    __syncthreads();
#pragma unroll
    for (int j = 0; j < 2; ++j) {
      int c   = (wv * 2 + j) * 64 + lane;
      int row = c >> 2;
      int kc  = (c & 3) * 8;
      gload_lds16(A + (size_t)(m0 + row) * K + k0 + kc,
                  As + (size_t)(wv * 2 + j) * 512);
      gload_lds16(W + (size_t)(n0 + row) * K + k0 + kc,
                  Bs + (size_t)(wv * 2 + j) * 512);
    }
    asm volatile("s_waitcnt vmcnt(0)" ::: "memory");
    __syncthreads();
    bf16x8 af[4], bw[4];
#pragma unroll
    for (int i = 0; i < 4; i++)
      af[i] = *reinterpret_cast<const bf16x8*>(As + (wm + i * 16 + arow) * BK + kgrp);
#pragma unroll
    for (int i = 0; i < 4; i++)
      bw[i] = *reinterpret_cast<const bf16x8*>(Bs + (wn + i * 16 + arow) * BK + kgrp);
#pragma unroll
    for (int i = 0; i < 4; i++)
#pragma unroll
      for (int j = 0; j < 4; j++)
        acc[i][j] = __builtin_amdgcn_mfma_f32_16x16x32_bf16(af[i], bw[j], acc[i][j], 0, 0, 0);
  }

  // epilogue. C/D layout: col = lane&15, row = (lane>>4)*4 + reg  [m89/m91]
#pragma unroll
  for (int i = 0; i < 4; i++) {
#pragma unroll
    for (int j = 0; j < 4; j++) {
#pragma unroll
      for (int r = 0; r < 4; r++) {
        int m = m0 + wm + i * 16 + (lane >> 4) * 4 + r;
        int n = n0 + wn + j * 16 + arow;
        float v = acc[i][j][r];
        if (MODE == 0) {
          Cf[(size_t)m * N + n] = v;
        } else {
          int bb = m >> 11, s = m & (S_ - 1);
          int h = n >> 6, d = n & 63;
          size_t oidx = ((size_t)(bb * H_ + h) * S_ + s) * HD_ + d;
          float other = __shfl_xor(v, 1, 64);
          if (blockIdx.z == 2) {
            Cv[oidx] = (__bf16)v;
          } else {
            int fi = d >> 1;
            float cs = tab[(s * 32 + fi) * 2];
            float sn = tab[(s * 32 + fi) * 2 + 1];
            float rv = (d & 1) ? (other * sn + v * cs) : (v * cs - other * sn);
            if (blockIdx.z == 0) rv *= SCL2;   // pre-scale Q: logits in exp2 domain
            __bf16* Co = (blockIdx.z == 0) ? Cq : Ck;
            Co[oidx] = (__bf16)rv;
          }
        }
      }
    }
  }
}

// V [bh][s][d=64] -> Vt [bh][d][s].  Tile 64s x 64d per block.
__global__ __launch_bounds__(256) void vtrans_kernel(
    const __bf16* __restrict__ V, __bf16* __restrict__ Vt) {
  __shared__ __attribute__((aligned(16))) char T[64 * 144]; // row d, 144B stride
  const int bh = blockIdx.y, s0 = blockIdx.x * 64;
  const __bf16* Vb = V + (size_t)bh * S_ * HD_;
  __bf16* Vtb = Vt + (size_t)bh * HD_ * S_;
  const int tid = threadIdx.x;
#pragma unroll
  for (int j = 0; j < 2; ++j) {
    int c = tid + j * 256;            // s = c>>3, dc = c&7
    int s = c >> 3, dc = c & 7;
    bf16x8 v = *reinterpret_cast<const bf16x8*>(Vb + (size_t)(s0 + s) * HD_ + dc * 8);
#pragma unroll
    for (int e = 0; e < 8; ++e) {
      int d = dc * 8 + e;
      int byt = (d * 144 + s * 2) ^ ((dc & 7) << 4);   // spread banks by dc
      *reinterpret_cast<__bf16*>(T + byt) = v[e];
    }
  }
  __syncthreads();
#pragma unroll
  for (int j = 0; j < 2; ++j) {
    int c = tid + j * 256;            // d = c>>3, sc = c&7
    int d = c >> 3, sc = c & 7;
    int byt = (d * 144 + sc * 16) ^ (((d >> 3) & 7) << 4);
    bf16x8 o = *reinterpret_cast<const bf16x8*>(T + byt);
    *reinterpret_cast<bf16x8*>(Vtb + (size_t)d * S_ + s0 + sc * 8) = o;
  }
}

// Flash attention, causal. Grid: (bh=32, pr=16). Block: 4 waves x 16 q-rows,
// paired q-tiles (pr, 31-pr) => uniform 33 kv-iters per block.
// Swapped QK^T: sc = mfma(K_frag, Q_frag) -> D[key][q], q = lane&15.
// K staged with key-permutation kph so each lane's 16 P-values are exactly
// the PV B-fragment (k = (lane>>4)*8+i) -> softmax + P fully in registers.
__global__ __launch_bounds__(256) void attn_kernel(
    const __bf16* __restrict__ Q, const __bf16* __restrict__ K,
    const __bf16* __restrict__ Vt, __bf16* __restrict__ O) {
  __shared__ __attribute__((aligned(16))) __bf16 Ks[2][64 * 64];
  __shared__ __attribute__((aligned(16))) __bf16 Vs[2][64 * 64];
  const int tid = threadIdx.x, lane = tid & 63, wv = tid >> 6;
  const int bh = blockIdx.x;
  const int pr = blockIdx.y;
  const int b = bh >> 4, h = bh & 15;
  const __bf16* Qb  = Q  + (size_t)bh * S_ * HD_;
  const __bf16* Kb  = K  + (size_t)bh * S_ * HD_;
  const __bf16* Vtb = Vt + (size_t)bh * HD_ * S_;
  const int arow = lane & 15, g = lane >> 4;

  // Ks row permutation: logical row L = ct*16 + rw  holds physical key
  // kph = (ct>>1)*32 + (rw>>2)*8 + (ct&1)*4 + (rw&3)
#define STAGE(K0, BK_, BV_)                                                   \
  do {                                                                        \
    _Pragma("unroll") for (int j = 0; j < 2; ++j) {                           \
      int G = (wv * 2 + j) * 64 + lane;                                       \
      int row = G >> 3, qq = G & 7;                                           \
      int qs = qq ^ (row & 7);                                                \
      int ctp = row >> 4, rw = row & 15;                                      \
      int kph = ((ctp >> 1) << 5) + ((rw >> 2) << 3) + ((ctp & 1) << 2)       \
                + (rw & 3);                                                   \
      gload_lds16(Kb + (size_t)((K0) + kph) * HD_ + qs * 8,                   \
                  (BK_) + (wv * 2 + j) * 512);                                \
      gload_lds16(Vtb + (size_t)row * S_ + (K0) + qs * 8,                     \
                  (BV_) + (wv * 2 + j) * 512);                                \
    }                                                                         \
  } while (0)

  for (int seg = 0; seg < 2; ++seg) {
    const int qt = (seg == 0) ? pr : 31 - pr;
    const int q0 = qt * 64;
    const int nkv = qt + 1;
    const int qw = q0 + wv * 16;
    const int qg = qw + arow;          // this thread's q-row

    bf16x8 aq[2];
#pragma unroll
    for (int j = 0; j < 2; j++)
      aq[j] = *reinterpret_cast<const bf16x8*>(
          Qb + (size_t)(qw + arow) * HD_ + j * 32 + g * 8);

    f32x4 po[4];
#pragma unroll
    for (int dt = 0; dt < 4; dt++) po[dt] = f32x4{0.f, 0.f, 0.f, 0.f};
    float mrow = -1e30f, lrow = 0.f;

    STAGE(0, Ks[0], Vs[0]);
    asm volatile("s_waitcnt vmcnt(0)" ::: "memory");
    __syncthreads();

    for (int kt = 0; kt < nkv; ++kt) {
      const int k0 = kt * 64;
      const int cur = kt & 1;
      if (kt + 1 < nkv) STAGE(k0 + 64, Ks[cur ^ 1], Vs[cur ^ 1]);
      const __bf16* Kc = Ks[cur];
      const __bf16* Vc = Vs[cur];

      // S^T = K Q^T : D[key][q], 8 MFMA. kb: A-frag rows = logical keys.
      f32x4 sc4[4];
      __builtin_amdgcn_s_setprio(1);
#pragma unroll
      for (int ct = 0; ct < 4; ct++) {
        sc4[ct] = f32x4{0.f, 0.f, 0.f, 0.f};
        int L = ct * 16 + arow;
#pragma unroll
        for (int j2 = 0; j2 < 2; j2++) {
          int byt = (L * 128 + j2 * 64 + g * 16) ^ ((L & 7) << 4);
          bf16x8 kb = *reinterpret_cast<const bf16x8*>((const char*)Kc + byt);
          sc4[ct] = __builtin_amdgcn_mfma_f32_16x16x32_bf16(kb, aq[j2], sc4[ct], 0, 0, 0);
        }
      }
      __builtin_amdgcn_s_setprio(0);

      // causal mask (diagonal tile only). sc4[ct][r] is physical key
      // k0 + (ct>>1)*32 + g*8 + (ct&1)*4 + r, q = qg.
      const bool full = (kt < nkv - 1);
      if (!full) {
#pragma unroll
        for (int ct = 0; ct < 4; ct++) {
          int kb0 = k0 + ((ct >> 1) << 5) + ((ct & 1) << 2) + g * 8;
#pragma unroll
          for (int r = 0; r < 4; r++)
            if (kb0 + r > qg) sc4[ct][r] = -1e30f;
        }
      }

      // in-register online softmax (one q-row per lane)
      float mx = -1e30f;
#pragma unroll
      for (int ct = 0; ct < 4; ct++)
#pragma unroll
        for (int r = 0; r < 4; r++) mx = fmaxf(mx, sc4[ct][r]);
      mx = fmaxf(mx, __shfl_xor(mx, 16, 64));
      mx = fmaxf(mx, __shfl_xor(mx, 32, 64));

      // defer-max (T13): skip rescale while growth bounded
      bool noskip = !__all(mx <= mrow + 11.0f);
      if (noskip) {
        float mnew = fmaxf(mrow, mx);
        float corr = fexp2(mrow - mnew);
        mrow = mnew;
        lrow *= corr;
#pragma unroll
        for (int dt = 0; dt < 4; dt++)
#pragma unroll
          for (int r = 0; r < 4; r++) po[dt][r] *= corr;
      }

      float rs = 0.f;
      float pv[4][4];
#pragma unroll
      for (int ct = 0; ct < 4; ct++)
#pragma unroll
        for (int r = 0; r < 4; r++) {
          float e = fexp2(sc4[ct][r] - mrow);
          pv[ct][r] = e;
          rs += e;
        }
      rs += __shfl_xor(rs, 16, 64);
      rs += __shfl_xor(rs, 32, 64);
      lrow += rs;

      // pack P: pb[j2] holds physical keys j2*32 + g*8 .. +7 (lane-local!)
      bf16x8 pb[2];
#pragma unroll
      for (int j2 = 0; j2 < 2; j2++) {
#pragma unroll
        for (int r = 0; r < 4; r++) {
          pb[j2][r]     = (__bf16)pv[2 * j2][r];
          pb[j2][4 + r] = (__bf16)pv[2 * j2 + 1][r];
        }
      }

      // O^T += V^T P^T : po[dt] = D[d][q], d = dt*16 + g*4 + r, q = arow
      __builtin_amdgcn_s_setprio(1);
#pragma unroll
      for (int dt = 0; dt < 4; dt++) {
        int d = dt * 16 + arow;
#pragma unroll
        for (int j2 = 0; j2 < 2; j2++) {
          int byv = (d * 128 + j2 * 64 + g * 16) ^ ((d & 7) << 4);
          bf16x8 vb = *reinterpret_cast<const bf16x8*>((const char*)Vc + byv);
          po[dt] = __builtin_amdgcn_mfma_f32_16x16x32_bf16(vb, pb[j2], po[dt], 0, 0, 0);
        }
      }
      __builtin_amdgcn_s_setprio(0);

      asm volatile("s_waitcnt vmcnt(0)" ::: "memory");
      __syncthreads();
    }

    // write: thread owns q = qg, d = dt*16 + g*4 + {0..3}
    float inv = __builtin_amdgcn_rcpf(lrow);
#pragma unroll
    for (int dt = 0; dt < 4; dt++) {
      bf16x4 o4;
#pragma unroll
      for (int r = 0; r < 4; r++) o4[r] = (__bf16)(po[dt][r] * inv);
      *reinterpret_cast<bf16x4*>(
          O + (size_t)(b * S_ + qg) * D_ + h * HD_ + dt * 16 + g * 4) = o4;
    }
  }
#undef STAGE
}

extern "C" void kernel_launch(void* const* d_in, const int* in_sizes, int n_in,
                              void* d_out, int out_size, void* d_ws, size_t ws_size,
                              hipStream_t stream) {
  const float* x  = (const float*)d_in[0];
  const float* wq = (const float*)d_in[1];
  const float* wk = (const float*)d_in[2];
  const float* wv = (const float*)d_in[3];
  const float* wo = (const float*)d_in[4];
  float* out = (float*)d_out;

  char* w = (char*)d_ws;
  __bf16* xb  = (__bf16*)(w);                    // 8 MB (reused as Vt later)
  __bf16* wqb = (__bf16*)(w + (8u  << 20));      // 2 MB each
  __bf16* wkb = (__bf16*)(w + (10u << 20));
  __bf16* wvb = (__bf16*)(w + (12u << 20));
  __bf16* wob = (__bf16*)(w + (14u << 20));
  __bf16* qws = (__bf16*)(w + (16u << 20));      // 8 MB each, [B][H][S][hd]
  __bf16* kws = (__bf16*)(w + (24u << 20));
  __bf16* vws = (__bf16*)(w + (32u << 20));
  __bf16* aws = (__bf16*)(w + (40u << 20));      // attn out, [token][feature]
  float*  tab = (float*)(w + (48u << 20));       // 512 KB rope table
  __bf16* vtw = xb;                              // Vt overlays xb (dead after QKV)

  cvt_bf16_kernel<<<M_ * D_ / 4 / 256, 256, 0, stream>>>(x,  xb,  M_ * D_ / 4);
  cvt_bf16_kernel<<<D_ * D_ / 4 / 256, 256, 0, stream>>>(wq, wqb, D_ * D_ / 4);
  cvt_bf16_kernel<<<D_ * D_ / 4 / 256, 256, 0, stream>>>(wk, wkb, D_ * D_ / 4);
  cvt_bf16_kernel<<<D_ * D_ / 4 / 256, 256, 0, stream>>>(wv, wvb, D_ * D_ / 4);
  cvt_bf16_kernel<<<D_ * D_ / 4 / 256, 256, 0, stream>>>(wo, wob, D_ * D_ / 4);
  rope_table_kernel<<<(S_ * 32) / 256, 256, 0, stream>>>(tab);

  dim3 g1(M_ / 128, D_ / 128, 3);
  gemm_bt<1><<<g1, 256, 0, stream>>>(xb, wqb, wkb, wvb,
                                     nullptr, qws, kws, vws, tab, M_, D_, D_);
  vtrans_kernel<<<dim3(S_ / 64, 2 * H_), 256, 0, stream>>>(vws, vtw);
  attn_kernel<<<dim3(2 * H_, S_ / 128), 256, 0, stream>>>(qws, kws, vtw, aws);
  dim3 g0(M_ / 128, D_ / 128, 1);
  gemm_bt<0><<<g0, 256, 0, stream>>>(aws, wob, wob, wob,
                                     out, nullptr, nullptr, nullptr, nullptr,
                                     M_, D_, D_);
}